// Round 2
// baseline (1034.252 us; speedup 1.0000x reference)
//
#include <hip/hip_runtime.h>
#include <hip/hip_fp16.h>
#include <stdint.h>

// Luong attention: out = softmax(Q K^T) K,  B=16, Tq=Tk=D=1024, fp32 in/out.
// Pipeline: [cvt] enc fp32 -> enc16 (row-major) + encT16 (transposed), both fp16
//           [scores] P16 = softmax_rows(Q K^T)  (fp16 MFMA, fp32 accum, S-resident)
//           [ctx]    out = P16 @ enc  (fp16 MFMA NT GEMM via encT16)
// Workspace: enc16 32MiB | encT16 32MiB | P16 32MiB  = 96MiB required.
//
// K-loops use raw s_barrier + hand-counted vmcnt so global_load_lds prefetch
// stays in flight across barriers (std __syncthreads drains vmcnt(0) -> m97 stall).

typedef _Float16 half_t;
typedef __attribute__((ext_vector_type(8))) _Float16 f16x8;
typedef __attribute__((ext_vector_type(4))) float f32x4;

#define RAW_BARRIER() asm volatile("s_barrier" ::: "memory")
#define WAIT_LGKM0()  asm volatile("s_waitcnt lgkmcnt(0)" ::: "memory")

__device__ __forceinline__ void gld_lds16(const void* g, void* l) {
    // async global->LDS, 16B per lane; LDS dest = wave-uniform base + lane*16
    __builtin_amdgcn_global_load_lds(
        (const __attribute__((address_space(1))) uint32_t*)g,
        (__attribute__((address_space(3))) uint32_t*)l, 16, 0, 0);
}

// ---------------------------------------------------------------------------
// Kernel 1: convert encoder to fp16, plain + transposed (LDS-tiled 64x64)
// grid (kt=16, dt=16, b=16), block 256
// ---------------------------------------------------------------------------
__global__ __launch_bounds__(256) void cvt_kernel(
    const float* __restrict__ enc, half_t* __restrict__ enc16,
    half_t* __restrict__ encT16) {
    __shared__ half_t lt[64 * 65];  // [k][d], pad 65 to break bank conflicts
    const int b = blockIdx.z, kt = blockIdx.x, dt = blockIdx.y;
    const int t = threadIdx.x;
    const int r = t >> 2;          // row within tile (k for load, d for store)
    const int c = (t & 3) << 4;    // 16-elem column segment
    const size_t bofs = (size_t)b << 20;

    const float* src = enc + bofs + (size_t)(kt * 64 + r) * 1024 + dt * 64 + c;
    union { half_t h[16]; uint4 q[2]; } v;
#pragma unroll
    for (int i = 0; i < 16; ++i) v.h[i] = (half_t)src[i];

    uint4* dst = (uint4*)(enc16 + bofs + (size_t)(kt * 64 + r) * 1024 + dt * 64 + c);
    dst[0] = v.q[0];
    dst[1] = v.q[1];

#pragma unroll
    for (int i = 0; i < 16; ++i) lt[r * 65 + c + i] = v.h[i];
    __syncthreads();

    union { half_t h[16]; uint4 q[2]; } w;
#pragma unroll
    for (int i = 0; i < 16; ++i) w.h[i] = lt[(c + i) * 65 + r];
    uint4* dstT = (uint4*)(encT16 + bofs + (size_t)(dt * 64 + r) * 1024 + kt * 64 + c);
    dstT[0] = w.q[0];
    dstT[1] = w.q[1];
}

// ---------------------------------------------------------------------------
// Kernel 2: S-resident scores + softmax.  grid 256 blocks x 512 thr (8 waves).
// Block = (batch, 64 q-rows). Wave w owns key-cols {h*512 + w*64 .. +64} for
// h=0,1. acc[rb][h*4+cb] : 16x16 C-frags -> 128 VGPR/lane.
// K staged per (d-chunk 32, key-half 512) = 32KB fp16, double buffered (64KB).
// ---------------------------------------------------------------------------
__global__ __launch_bounds__(512, 2) void scores_kernel(
    const float* __restrict__ dec, const half_t* __restrict__ enc16,
    half_t* __restrict__ p16) {
    __shared__ char smem[65536];
    float* red  = (float*)smem;           // [8][64] (aliases kbuf0, used after GEMM)
    float* redg = (float*)(smem + 2048);  // [64]

    const int l = blockIdx.x;
    const int xcd = l & 7, idx = l >> 3;
    const int b = xcd + ((idx >> 4) << 3);   // 2 batches per XCD -> K fits L2
    const int qbase = (idx & 15) * 64;

    const int tid = threadIdx.x;
    const int w = tid >> 6, lane = tid & 63, quad = lane >> 4, n16 = lane & 15;
    const size_t bofs = (size_t)b << 20;

    f32x4 acc[4][8];
#pragma unroll
    for (int rb = 0; rb < 4; ++rb)
#pragma unroll
        for (int cf = 0; cf < 8; ++cf) acc[rb][cf] = (f32x4){0.f, 0.f, 0.f, 0.f};

    // ---- stage helper: stage s covers d-chunk (s>>1)*32, key-half (s&1)*512
    // 4 global_load_lds (16B/lane) per wave per stage.
    auto stage = [&](int s, int sel) {
        half_t* buf = (half_t*)(smem + (sel << 15));
        const int dc = (s >> 1) << 5;
        const int kh = (s & 1) << 9;
#pragma unroll
        for (int j = 0; j < 4; ++j) {
            const int lin = w * 256 + j * 64 + lane;                 // 16B unit id
            const half_t* gp = enc16 + bofs + (size_t)(kh + (lin >> 2)) * 1024
                               + dc + ((lin & 3) << 3);
            gld_lds16(gp, buf + (size_t)(w * 256 + j * 64) * 8);     // uniform base
        }
    };

    f16x8 afrag[4];
    float4 qlo[4], qhi[4];
    stage(0, 0);
    for (int it = 0; it < 64; ++it) {
        const int cur = it & 1;
        const int dc = (it >> 1) << 5;
        if ((it & 1) == 0) {
            // Issue Q loads FIRST so the compiler's wait for them (vmcnt(4))
            // does not drain the next-stage prefetch.
#pragma unroll
            for (int rb = 0; rb < 4; ++rb) {
                const float* qp = dec + bofs
                                  + (size_t)(qbase + rb * 16 + n16) * 1024
                                  + dc + quad * 8;
                qlo[rb] = *(const float4*)qp;
                qhi[rb] = *(const float4*)(qp + 4);
            }
        }
        if (it < 63) {
            stage(it + 1, cur ^ 1);
            if ((it & 1) == 0)
                // outstanding: 4 cur-stage (oldest) + 8 Q + 4 next-stage
                asm volatile("s_waitcnt vmcnt(12)" ::: "memory");
            else
                // outstanding: 4 cur-stage (oldest) + 4 next-stage
                asm volatile("s_waitcnt vmcnt(4)" ::: "memory");
        } else {
            asm volatile("s_waitcnt vmcnt(0)" ::: "memory");
        }
        RAW_BARRIER();  // all waves' cur-stage loads have landed in LDS

        if ((it & 1) == 0) {
#pragma unroll
            for (int rb = 0; rb < 4; ++rb) {
                f16x8 a;
                a[0] = (half_t)qlo[rb].x; a[1] = (half_t)qlo[rb].y;
                a[2] = (half_t)qlo[rb].z; a[3] = (half_t)qlo[rb].w;
                a[4] = (half_t)qhi[rb].x; a[5] = (half_t)qhi[rb].y;
                a[6] = (half_t)qhi[rb].z; a[7] = (half_t)qhi[rb].w;
                afrag[rb] = a;
            }
        }
        const half_t* curb = (const half_t*)(smem + (cur << 15));
        f16x8 bfrag[4];
#pragma unroll
        for (int cb = 0; cb < 4; ++cb) {
            const int row = w * 64 + cb * 16 + n16;   // key within staged half
            bfrag[cb] = *(const f16x8*)(curb + row * 32 + quad * 8);
        }
        const int hb = (it & 1) << 2;
#pragma unroll
        for (int rb = 0; rb < 4; ++rb)
#pragma unroll
            for (int cb = 0; cb < 4; ++cb)
                acc[rb][hb + cb] = __builtin_amdgcn_mfma_f32_16x16x32_f16(
                    afrag[rb], bfrag[cb], acc[rb][hb + cb], 0, 0, 0);
        WAIT_LGKM0();   // ds_reads complete before buffer can be overwritten
        RAW_BARRIER();
    }

    // ---- softmax over the 1024 cols held across the 8 waves ----
    float mrow[4][4], srow[4][4];
#pragma unroll
    for (int rb = 0; rb < 4; ++rb)
#pragma unroll
        for (int r = 0; r < 4; ++r) {
            float m = -1e30f;
#pragma unroll
            for (int cf = 0; cf < 8; ++cf) m = fmaxf(m, acc[rb][cf][r]);
#pragma unroll
            for (int off = 1; off < 16; off <<= 1)
                m = fmaxf(m, __shfl_xor(m, off, 64));
            mrow[rb][r] = m;
        }
    if (n16 == 0) {
#pragma unroll
        for (int rb = 0; rb < 4; ++rb)
#pragma unroll
            for (int r = 0; r < 4; ++r)
                red[w * 64 + rb * 16 + quad * 4 + r] = mrow[rb][r];
    }
    __syncthreads();
    if (tid < 64) {
        float g = red[tid];
#pragma unroll
        for (int ww = 1; ww < 8; ++ww) g = fmaxf(g, red[ww * 64 + tid]);
        redg[tid] = g;
    }
    __syncthreads();
#pragma unroll
    for (int rb = 0; rb < 4; ++rb)
#pragma unroll
        for (int r = 0; r < 4; ++r) mrow[rb][r] = redg[rb * 16 + quad * 4 + r];
    __syncthreads();  // done reading maxes; red reused for sums

#pragma unroll
    for (int rb = 0; rb < 4; ++rb)
#pragma unroll
        for (int r = 0; r < 4; ++r) {
            float s = 0.f;
#pragma unroll
            for (int cf = 0; cf < 8; ++cf) {
                float p = __expf(acc[rb][cf][r] - mrow[rb][r]);
                acc[rb][cf][r] = p;
                s += p;
            }
#pragma unroll
            for (int off = 1; off < 16; off <<= 1) s += __shfl_xor(s, off, 64);
            srow[rb][r] = s;
        }
    if (n16 == 0) {
#pragma unroll
        for (int rb = 0; rb < 4; ++rb)
#pragma unroll
            for (int r = 0; r < 4; ++r)
                red[w * 64 + rb * 16 + quad * 4 + r] = srow[rb][r];
    }
    __syncthreads();
    if (tid < 64) {
        float g = 0.f;
#pragma unroll
        for (int ww = 0; ww < 8; ++ww) g += red[ww * 64 + tid];
        redg[tid] = g;
    }
    __syncthreads();
#pragma unroll
    for (int rb = 0; rb < 4; ++rb)
#pragma unroll
        for (int r = 0; r < 4; ++r)
            srow[rb][r] = 1.0f / redg[rb * 16 + quad * 4 + r];

    // ---- store normalized P as fp16 ----
#pragma unroll
    for (int rb = 0; rb < 4; ++rb)
#pragma unroll
        for (int cf = 0; cf < 8; ++cf) {
            const int col = ((cf >> 2) << 9) + w * 64 + ((cf & 3) << 4) + n16;
#pragma unroll
            for (int r = 0; r < 4; ++r) {
                const int row = qbase + rb * 16 + quad * 4 + r;
                p16[bofs + (size_t)row * 1024 + col] =
                    (half_t)(acc[rb][cf][r] * srow[rb][r]);
            }
        }
}

// ---------------------------------------------------------------------------
// Kernel 3: out = P16 @ enc (NT via encT16). m97-style 128x128xBK32 fp16 GEMM.
// grid 1024 blocks x 256 thr (4 waves, each 64x64).
// ---------------------------------------------------------------------------
__global__ __launch_bounds__(256, 2) void ctx_kernel(
    const half_t* __restrict__ p16, const half_t* __restrict__ encT16,
    float* __restrict__ out) {
    __shared__ char smem[32768];  // abuf[2] @0/8192, bbuf[2] @16384/24576

    const int l = blockIdx.x;
    const int xcd = l & 7, idx = l >> 3;           // idx 0..127
    const int b = xcd + ((idx >> 6) << 3);
    const int tl = idx & 63;
    const int tm = tl >> 3, tn = tl & 7;
    const int tid = threadIdx.x;
    const int w = tid >> 6, lane = tid & 63, quad = lane >> 4, n16 = lane & 15;
    const int wr = w >> 1, wc = w & 1;
    const size_t bofs = (size_t)b << 20;

    auto stage = [&](int ck, int sel) {
        half_t* ab = (half_t*)(smem + sel * 8192);
        half_t* bb = (half_t*)(smem + 16384 + sel * 8192);
        const int k0 = ck << 5;
#pragma unroll
        for (int j = 0; j < 2; ++j) {
            const int lin = w * 128 + j * 64 + lane;  // 16B unit id, 0..511
            const int row = lin >> 2, off = (lin & 3) << 3;
            const half_t* ga = p16 + bofs + (size_t)(tm * 128 + row) * 1024 + k0 + off;
            gld_lds16(ga, ab + (size_t)(w * 128 + j * 64) * 8);
            const half_t* gb = encT16 + bofs + (size_t)(tn * 128 + row) * 1024 + k0 + off;
            gld_lds16(gb, bb + (size_t)(w * 128 + j * 64) * 8);
        }
    };

    f32x4 acc[4][4];
#pragma unroll
    for (int i = 0; i < 4; ++i)
#pragma unroll
        for (int j = 0; j < 4; ++j) acc[i][j] = (f32x4){0.f, 0.f, 0.f, 0.f};

    stage(0, 0);
    for (int ck = 0; ck < 32; ++ck) {
        const int cur = ck & 1;
        if (ck < 31) {
            stage(ck + 1, cur ^ 1);
            // outstanding: 4 cur (oldest) + 4 next
            asm volatile("s_waitcnt vmcnt(4)" ::: "memory");
        } else {
            asm volatile("s_waitcnt vmcnt(0)" ::: "memory");
        }
        RAW_BARRIER();

        const half_t* acur = (const half_t*)(smem + cur * 8192);
        const half_t* bcur = (const half_t*)(smem + 16384 + cur * 8192);
        f16x8 af[4], bf[4];
#pragma unroll
        for (int i = 0; i < 4; ++i) {
            af[i] = *(const f16x8*)(acur + (wr * 64 + i * 16 + n16) * 32 + quad * 8);
            bf[i] = *(const f16x8*)(bcur + (wc * 64 + i * 16 + n16) * 32 + quad * 8);
        }
#pragma unroll
        for (int i = 0; i < 4; ++i)
#pragma unroll
            for (int j = 0; j < 4; ++j)
                acc[i][j] = __builtin_amdgcn_mfma_f32_16x16x32_f16(
                    af[i], bf[j], acc[i][j], 0, 0, 0);
        WAIT_LGKM0();
        RAW_BARRIER();
    }

#pragma unroll
    for (int i = 0; i < 4; ++i)
#pragma unroll
        for (int j = 0; j < 4; ++j)
#pragma unroll
            for (int r = 0; r < 4; ++r)
                out[bofs
                    + (size_t)(tm * 128 + wr * 64 + i * 16 + quad * 4 + r) * 1024
                    + tn * 128 + wc * 64 + j * 16 + n16] = acc[i][j][r];
}

extern "C" void kernel_launch(void* const* d_in, const int* in_sizes, int n_in,
                              void* d_out, int out_size, void* d_ws, size_t ws_size,
                              hipStream_t stream) {
    (void)in_sizes; (void)n_in; (void)out_size;
    const float* dec = (const float*)d_in[0];   // decoder_hidden  [16,1024,1024] f32
    const float* enc = (const float*)d_in[1];   // encoder_outputs [16,1024,1024] f32
    float* out = (float*)d_out;

    // workspace: enc16 | encT16 | P16, 32MiB each (requires ws_size >= 96MiB)
    half_t* enc16  = (half_t*)d_ws;
    half_t* encT16 = enc16 + ((size_t)16 << 20);
    half_t* p16    = encT16 + ((size_t)16 << 20);
    (void)ws_size;

    cvt_kernel<<<dim3(16, 16, 16), 256, 0, stream>>>(enc, enc16, encT16);
    scores_kernel<<<dim3(256), 512, 0, stream>>>(dec, enc16, p16);
    ctx_kernel<<<dim3(1024), 256, 0, stream>>>(p16, encT16, out);
}

// Round 3
// 303.728 us; speedup vs baseline: 3.4052x; 3.4052x over previous
//
#include <hip/hip_runtime.h>
#include <hip/hip_fp16.h>
#include <stdint.h>

// Luong attention: out = softmax(Q K^T) K,  B=16, Tq=Tk=D=1024, fp32 in/out.
// Pipeline: [cvt] enc fp32 -> enc16 (row-major) + encT16 (transposed), both fp16
//           [scores] P16 = softmax_rows(Q K^T)  (fp16 MFMA, fp32 accum, S-resident)
//           [ctx]    out = P16 @ enc  (fp16 MFMA NT GEMM via encT16)
// Workspace: enc16 32MiB | encT16 32MiB | P16 32MiB  = 96MiB required.
//
// R2 lesson: acc[][] must be statically indexed (runtime idx -> scratch spill,
// 4 GB of spill traffic, 850us). K-loop is unrolled x2 so buffer parity and
// accumulator half-select are compile-time constants.

typedef _Float16 half_t;
typedef __attribute__((ext_vector_type(8))) _Float16 f16x8;
typedef __attribute__((ext_vector_type(4))) float f32x4;

#define RAW_BARRIER() asm volatile("s_barrier" ::: "memory")
#define WAIT_LGKM0()  asm volatile("s_waitcnt lgkmcnt(0)" ::: "memory")

__device__ __forceinline__ void gld_lds16(const void* g, void* l) {
    // async global->LDS, 16B per lane; LDS dest = wave-uniform base + lane*16
    __builtin_amdgcn_global_load_lds(
        (const __attribute__((address_space(1))) uint32_t*)g,
        (__attribute__((address_space(3))) uint32_t*)l, 16, 0, 0);
}

// ---------------------------------------------------------------------------
// Kernel 1: convert encoder to fp16, plain + transposed (LDS-tiled 64x64)
// grid (kt=16, dt=16, b=16), block 256
// ---------------------------------------------------------------------------
__global__ __launch_bounds__(256) void cvt_kernel(
    const float* __restrict__ enc, half_t* __restrict__ enc16,
    half_t* __restrict__ encT16) {
    __shared__ half_t lt[64 * 65];  // [k][d], pad 65 to break bank conflicts
    const int b = blockIdx.z, kt = blockIdx.x, dt = blockIdx.y;
    const int t = threadIdx.x;
    const int r = t >> 2;          // row within tile (k for load, d for store)
    const int c = (t & 3) << 4;    // 16-elem column segment
    const size_t bofs = (size_t)b << 20;

    const float* src = enc + bofs + (size_t)(kt * 64 + r) * 1024 + dt * 64 + c;
    union { half_t h[16]; uint4 q[2]; } v;
#pragma unroll
    for (int i = 0; i < 16; ++i) v.h[i] = (half_t)src[i];

    uint4* dst = (uint4*)(enc16 + bofs + (size_t)(kt * 64 + r) * 1024 + dt * 64 + c);
    dst[0] = v.q[0];
    dst[1] = v.q[1];

#pragma unroll
    for (int i = 0; i < 16; ++i) lt[r * 65 + c + i] = v.h[i];
    __syncthreads();

    union { half_t h[16]; uint4 q[2]; } w;
#pragma unroll
    for (int i = 0; i < 16; ++i) w.h[i] = lt[(c + i) * 65 + r];
    uint4* dstT = (uint4*)(encT16 + bofs + (size_t)(dt * 64 + r) * 1024 + kt * 64 + c);
    dstT[0] = w.q[0];
    dstT[1] = w.q[1];
}

// ---------------------------------------------------------------------------
// Kernel 2: S-resident scores + softmax.  grid 256 blocks x 512 thr (8 waves).
// Block = (batch, 64 q-rows). Wave w owns key-cols {h*512 + w*64 .. +64} for
// h=0,1. acc[rb][h*4+cb] : 16x16 C-frags -> 128 VGPR/lane (STATIC indices!).
// K staged per (d-chunk 32, key-half 512) = 32KB fp16, double buffered (64KB).
// Raw s_barrier + hand-counted vmcnt keeps prefetch in flight across barriers.
// ---------------------------------------------------------------------------
__global__ __launch_bounds__(512, 2) void scores_kernel(
    const float* __restrict__ dec, const half_t* __restrict__ enc16,
    half_t* __restrict__ p16) {
    __shared__ char smem[65536];
    float* red  = (float*)smem;           // [8][64] (aliases kbuf0, used after GEMM)
    float* redg = (float*)(smem + 2048);  // [64]

    const int l = blockIdx.x;
    const int xcd = l & 7, idx = l >> 3;
    const int b = xcd + ((idx >> 4) << 3);   // 2 batches per XCD -> K fits L2
    const int qbase = (idx & 15) * 64;

    const int tid = threadIdx.x;
    const int w = tid >> 6, lane = tid & 63, quad = lane >> 4, n16 = lane & 15;
    const size_t bofs = (size_t)b << 20;

    f32x4 acc[4][8];
#pragma unroll
    for (int rb = 0; rb < 4; ++rb)
#pragma unroll
        for (int cf = 0; cf < 8; ++cf) acc[rb][cf] = (f32x4){0.f, 0.f, 0.f, 0.f};

    // ---- stage helper: stage s covers d-chunk (s>>1)*32, key-half (s&1)*512
    // 4 global_load_lds (16B/lane) per wave per stage. Buffer = s&1 (static).
    auto stage = [&](int s, int sel) {
        half_t* buf = (half_t*)(smem + (sel << 15));
        const int dc = (s >> 1) << 5;
        const int kh = (s & 1) << 9;
#pragma unroll
        for (int j = 0; j < 4; ++j) {
            const int lin = w * 256 + j * 64 + lane;                 // 16B unit id
            const half_t* gp = enc16 + bofs + (size_t)(kh + (lin >> 2)) * 1024
                               + dc + ((lin & 3) << 3);
            gld_lds16(gp, buf + (size_t)(w * 256 + j * 64) * 8);     // uniform base
        }
    };

    stage(0, 0);
    for (int itp = 0; itp < 32; ++itp) {
        const int dc = itp << 5;

        // ===== even phase: stage s0=2*itp in buf0, compute acc[..][0..3] =====
        // Issue Q loads FIRST so the compiler's wait for them does not drain
        // the next-stage prefetch.
        float4 qlo[4], qhi[4];
#pragma unroll
        for (int rb = 0; rb < 4; ++rb) {
            const float* qp = dec + bofs
                              + (size_t)(qbase + rb * 16 + n16) * 1024
                              + dc + quad * 8;
            qlo[rb] = *(const float4*)qp;
            qhi[rb] = *(const float4*)(qp + 4);
        }
        stage(2 * itp + 1, 1);   // prefetch odd half into buf1
        // outstanding: 4 cur-stage (oldest) + 8 Q + 4 next-stage
        asm volatile("s_waitcnt vmcnt(12)" ::: "memory");
        RAW_BARRIER();  // all waves' buf0 loads landed

        f16x8 afrag[4];
#pragma unroll
        for (int rb = 0; rb < 4; ++rb) {
            f16x8 a;
            a[0] = (half_t)qlo[rb].x; a[1] = (half_t)qlo[rb].y;
            a[2] = (half_t)qlo[rb].z; a[3] = (half_t)qlo[rb].w;
            a[4] = (half_t)qhi[rb].x; a[5] = (half_t)qhi[rb].y;
            a[6] = (half_t)qhi[rb].z; a[7] = (half_t)qhi[rb].w;
            afrag[rb] = a;
        }
        {
            const half_t* curb = (const half_t*)smem;  // buf0
            f16x8 bfrag[4];
#pragma unroll
            for (int cb = 0; cb < 4; ++cb) {
                const int row = w * 64 + cb * 16 + n16;   // key within staged half
                bfrag[cb] = *(const f16x8*)(curb + row * 32 + quad * 8);
            }
#pragma unroll
            for (int rb = 0; rb < 4; ++rb)
#pragma unroll
                for (int cb = 0; cb < 4; ++cb)
                    acc[rb][cb] = __builtin_amdgcn_mfma_f32_16x16x32_f16(
                        afrag[rb], bfrag[cb], acc[rb][cb], 0, 0, 0);
        }
        WAIT_LGKM0();   // ds_reads complete before buf0 can be overwritten
        RAW_BARRIER();

        // ===== odd phase: buf1 current, prefetch next-pair even into buf0 ====
        if (itp < 31) {
            stage(2 * itp + 2, 0);
            asm volatile("s_waitcnt vmcnt(4)" ::: "memory");  // buf1's 4 done
        } else {
            asm volatile("s_waitcnt vmcnt(0)" ::: "memory");
        }
        RAW_BARRIER();
        {
            const half_t* curb = (const half_t*)(smem + 32768);  // buf1
            f16x8 bfrag[4];
#pragma unroll
            for (int cb = 0; cb < 4; ++cb) {
                const int row = w * 64 + cb * 16 + n16;
                bfrag[cb] = *(const f16x8*)(curb + row * 32 + quad * 8);
            }
#pragma unroll
            for (int rb = 0; rb < 4; ++rb)
#pragma unroll
                for (int cb = 0; cb < 4; ++cb)
                    acc[rb][4 + cb] = __builtin_amdgcn_mfma_f32_16x16x32_f16(
                        afrag[rb], bfrag[cb], acc[rb][4 + cb], 0, 0, 0);
        }
        WAIT_LGKM0();
        RAW_BARRIER();
    }

    // ---- softmax over the 1024 cols held across the 8 waves ----
    float mrow[4][4], srow[4][4];
#pragma unroll
    for (int rb = 0; rb < 4; ++rb)
#pragma unroll
        for (int r = 0; r < 4; ++r) {
            float m = -1e30f;
#pragma unroll
            for (int cf = 0; cf < 8; ++cf) m = fmaxf(m, acc[rb][cf][r]);
#pragma unroll
            for (int off = 1; off < 16; off <<= 1)
                m = fmaxf(m, __shfl_xor(m, off, 64));
            mrow[rb][r] = m;
        }
    if (n16 == 0) {
#pragma unroll
        for (int rb = 0; rb < 4; ++rb)
#pragma unroll
            for (int r = 0; r < 4; ++r)
                red[w * 64 + rb * 16 + quad * 4 + r] = mrow[rb][r];
    }
    __syncthreads();
    if (tid < 64) {
        float g = red[tid];
#pragma unroll
        for (int ww = 1; ww < 8; ++ww) g = fmaxf(g, red[ww * 64 + tid]);
        redg[tid] = g;
    }
    __syncthreads();
#pragma unroll
    for (int rb = 0; rb < 4; ++rb)
#pragma unroll
        for (int r = 0; r < 4; ++r) mrow[rb][r] = redg[rb * 16 + quad * 4 + r];
    __syncthreads();  // done reading maxes; red reused for sums

#pragma unroll
    for (int rb = 0; rb < 4; ++rb)
#pragma unroll
        for (int r = 0; r < 4; ++r) {
            float s = 0.f;
#pragma unroll
            for (int cf = 0; cf < 8; ++cf) {
                float p = __expf(acc[rb][cf][r] - mrow[rb][r]);
                acc[rb][cf][r] = p;
                s += p;
            }
#pragma unroll
            for (int off = 1; off < 16; off <<= 1) s += __shfl_xor(s, off, 64);
            srow[rb][r] = s;
        }
    if (n16 == 0) {
#pragma unroll
        for (int rb = 0; rb < 4; ++rb)
#pragma unroll
            for (int r = 0; r < 4; ++r)
                red[w * 64 + rb * 16 + quad * 4 + r] = srow[rb][r];
    }
    __syncthreads();
    if (tid < 64) {
        float g = 0.f;
#pragma unroll
        for (int ww = 0; ww < 8; ++ww) g += red[ww * 64 + tid];
        redg[tid] = g;
    }
    __syncthreads();
#pragma unroll
    for (int rb = 0; rb < 4; ++rb)
#pragma unroll
        for (int r = 0; r < 4; ++r)
            srow[rb][r] = 1.0f / redg[rb * 16 + quad * 4 + r];

    // ---- store normalized P as fp16 ----
#pragma unroll
    for (int rb = 0; rb < 4; ++rb)
#pragma unroll
        for (int cf = 0; cf < 8; ++cf) {
            const int col = ((cf >> 2) << 9) + w * 64 + ((cf & 3) << 4) + n16;
#pragma unroll
            for (int r = 0; r < 4; ++r) {
                const int row = qbase + rb * 16 + quad * 4 + r;
                p16[bofs + (size_t)row * 1024 + col] =
                    (half_t)(acc[rb][cf][r] * srow[rb][r]);
            }
        }
}

// ---------------------------------------------------------------------------
// Kernel 3: out = P16 @ enc (NT via encT16). m97-style 128x128xBK32 fp16 GEMM.
// grid 1024 blocks x 256 thr (4 waves, each 64x64). Unrolled x2: static sel.
// ---------------------------------------------------------------------------
__global__ __launch_bounds__(256, 2) void ctx_kernel(
    const half_t* __restrict__ p16, const half_t* __restrict__ encT16,
    float* __restrict__ out) {
    __shared__ char smem[32768];  // abuf[2] @0/8192, bbuf[2] @16384/24576

    const int l = blockIdx.x;
    const int xcd = l & 7, idx = l >> 3;           // idx 0..127
    const int b = xcd + ((idx >> 6) << 3);
    const int tl = idx & 63;
    const int tm = tl >> 3, tn = tl & 7;
    const int tid = threadIdx.x;
    const int w = tid >> 6, lane = tid & 63, quad = lane >> 4, n16 = lane & 15;
    const int wr = w >> 1, wc = w & 1;
    const size_t bofs = (size_t)b << 20;

    auto stage = [&](int ck, int sel) {
        half_t* ab = (half_t*)(smem + sel * 8192);
        half_t* bb = (half_t*)(smem + 16384 + sel * 8192);
        const int k0 = ck << 5;
#pragma unroll
        for (int j = 0; j < 2; ++j) {
            const int lin = w * 128 + j * 64 + lane;  // 16B unit id, 0..511
            const int row = lin >> 2, off = (lin & 3) << 3;
            const half_t* ga = p16 + bofs + (size_t)(tm * 128 + row) * 1024 + k0 + off;
            gld_lds16(ga, ab + (size_t)(w * 128 + j * 64) * 8);
            const half_t* gb = encT16 + bofs + (size_t)(tn * 128 + row) * 1024 + k0 + off;
            gld_lds16(gb, bb + (size_t)(w * 128 + j * 64) * 8);
        }
    };

    f32x4 acc[4][4];
#pragma unroll
    for (int i = 0; i < 4; ++i)
#pragma unroll
        for (int j = 0; j < 4; ++j) acc[i][j] = (f32x4){0.f, 0.f, 0.f, 0.f};

    auto compute = [&](int sel) {
        const half_t* acur = (const half_t*)(smem + sel * 8192);
        const half_t* bcur = (const half_t*)(smem + 16384 + sel * 8192);
        f16x8 af[4], bf[4];
#pragma unroll
        for (int i = 0; i < 4; ++i) {
            af[i] = *(const f16x8*)(acur + (wr * 64 + i * 16 + n16) * 32 + quad * 8);
            bf[i] = *(const f16x8*)(bcur + (wc * 64 + i * 16 + n16) * 32 + quad * 8);
        }
#pragma unroll
        for (int i = 0; i < 4; ++i)
#pragma unroll
            for (int j = 0; j < 4; ++j)
                acc[i][j] = __builtin_amdgcn_mfma_f32_16x16x32_f16(
                    af[i], bf[j], acc[i][j], 0, 0, 0);
    };

    stage(0, 0);
    for (int cp = 0; cp < 16; ++cp) {
        // even chunk (buf0 current)
        stage(2 * cp + 1, 1);
        asm volatile("s_waitcnt vmcnt(4)" ::: "memory");
        RAW_BARRIER();
        compute(0);
        WAIT_LGKM0();
        RAW_BARRIER();
        // odd chunk (buf1 current)
        if (cp < 15) {
            stage(2 * cp + 2, 0);
            asm volatile("s_waitcnt vmcnt(4)" ::: "memory");
        } else {
            asm volatile("s_waitcnt vmcnt(0)" ::: "memory");
        }
        RAW_BARRIER();
        compute(1);
        WAIT_LGKM0();
        RAW_BARRIER();
    }

#pragma unroll
    for (int i = 0; i < 4; ++i)
#pragma unroll
        for (int j = 0; j < 4; ++j)
#pragma unroll
            for (int r = 0; r < 4; ++r)
                out[bofs
                    + (size_t)(tm * 128 + wr * 64 + i * 16 + quad * 4 + r) * 1024
                    + tn * 128 + wc * 64 + j * 16 + n16] = acc[i][j][r];
}

extern "C" void kernel_launch(void* const* d_in, const int* in_sizes, int n_in,
                              void* d_out, int out_size, void* d_ws, size_t ws_size,
                              hipStream_t stream) {
    (void)in_sizes; (void)n_in; (void)out_size;
    const float* dec = (const float*)d_in[0];   // decoder_hidden  [16,1024,1024] f32
    const float* enc = (const float*)d_in[1];   // encoder_outputs [16,1024,1024] f32
    float* out = (float*)d_out;

    // workspace: enc16 | encT16 | P16, 32MiB each (requires ws_size >= 96MiB)
    half_t* enc16  = (half_t*)d_ws;
    half_t* encT16 = enc16 + ((size_t)16 << 20);
    half_t* p16    = encT16 + ((size_t)16 << 20);
    (void)ws_size;

    cvt_kernel<<<dim3(16, 16, 16), 256, 0, stream>>>(enc, enc16, encT16);
    scores_kernel<<<dim3(256), 512, 0, stream>>>(dec, enc16, p16);
    ctx_kernel<<<dim3(1024), 256, 0, stream>>>(p16, encT16, out);
}

// Round 4
// 284.546 us; speedup vs baseline: 3.6347x; 1.0674x over previous
//
#include <hip/hip_runtime.h>
#include <hip/hip_fp16.h>
#include <stdint.h>

// Luong attention: out = softmax(Q K^T) K,  B=16, Tq=Tk=D=1024, fp32 in/out.
//
// R4 structure: all MFMA operands pre-swizzled to fragment-major layout
//   addr_halfs(r, c) = (c>>5)*32768 + r*32 + (c&31)     (per 1024x1024 batch)
// so a 16x16x32 MFMA fragment read (lane = n16*32 + quad*8) is a contiguous
// 1KB wave-coalesced global_load_dwordx4. K-loops have NO LDS and NO barriers
// (R3 lesson: zero cross-wave B reuse made LDS staging + 4 barriers/itp pure
// overhead; LDS pipe 640cyc vs MFMA 310cyc per phase, MfmaUtil 10%).
//
// [cvt]    dec f32 -> q16 (swizzled);  enc f32 -> encsw + encTsw (swizzled)
// [scores] S = Q K^T (frag loads from q16/encsw), softmax, P -> p16 (swizzled)
// [ctx]    out = P @ enc  (frag loads from p16/encTsw)
// p16 ALIASES q16 (each scores block overwrites exactly the rows it consumed).
// Workspace: q16/p16 32MiB | encsw 32MiB | encTsw 32MiB = 96MiB.

typedef _Float16 half_t;
typedef __attribute__((ext_vector_type(8))) _Float16 f16x8;
typedef __attribute__((ext_vector_type(4))) float f32x4;

// ---------------------------------------------------------------------------
// Kernel 1: fp32 -> fp16 swizzled layout. grid (rt=16, ct=16, z=32), block 256.
// z<16: dec batch z -> q16 (direct). z>=16: enc batch z-16 -> encsw (direct)
// + encTsw (LDS 64x64 transpose).
// ---------------------------------------------------------------------------
__global__ __launch_bounds__(256) void cvt_kernel(
    const float* __restrict__ dec, const float* __restrict__ enc,
    half_t* __restrict__ q16, half_t* __restrict__ encsw,
    half_t* __restrict__ encTsw) {
    __shared__ half_t lt[64 * 65];  // pad 65: conflict-free transpose
    const int z = blockIdx.z;
    const int isenc = z >> 4;
    const int b = z & 15;
    const int rt = blockIdx.x, ct = blockIdx.y;
    const int t = threadIdx.x;
    const int r = t >> 2;           // local row 0..63
    const int c0 = (t & 3) << 4;    // local col segment {0,16,32,48}
    const size_t bofs = (size_t)b << 20;

    const float* src = (isenc ? enc : dec) + bofs
                       + (size_t)(rt * 64 + r) * 1024 + ct * 64 + c0;
    union { half_t h[16]; uint4 q[2]; } v;
#pragma unroll
    for (int i = 0; i < 16; ++i) v.h[i] = (half_t)src[i];

    // direct swizzled write: element (gr, gc+i) -> (gc>>5)*32768 + gr*32 + (gc&31) + i
    {
        const int gr = rt * 64 + r, gc = ct * 64 + c0;
        half_t* dst = (isenc ? encsw : q16) + bofs
                      + (size_t)(gc >> 5) * 32768 + gr * 32 + (gc & 31);
        ((uint4*)dst)[0] = v.q[0];
        ((uint4*)dst)[1] = v.q[1];
    }

    if (isenc) {
#pragma unroll
        for (int i = 0; i < 16; ++i) lt[r * 65 + c0 + i] = v.h[i];
        __syncthreads();
        // thread now holds (key = rt*64 + c0 + i, d = ct*64 + r), keys contiguous
        union { half_t h[16]; uint4 q[2]; } w;
#pragma unroll
        for (int i = 0; i < 16; ++i) w.h[i] = lt[(c0 + i) * 65 + r];
        const int gk = rt * 64 + c0, gd = ct * 64 + r;
        half_t* dstT = encTsw + bofs
                       + (size_t)(gk >> 5) * 32768 + gd * 32 + (gk & 31);
        ((uint4*)dstT)[0] = w.q[0];
        ((uint4*)dstT)[1] = w.q[1];
    }
}

// ---------------------------------------------------------------------------
// Kernel 2: S-resident scores + softmax. grid 256 x 512 thr (8 waves).
// Block = (batch, 64 q-rows); wave w owns keys {h*512 + w*64 ..+64}, h=0,1.
// acc[4][8] 16x16 frags = 128 VGPR, all statically indexed.
// K-loop: 12 coalesced frag loads + 32 MFMA per dc, no LDS, no barriers.
// ---------------------------------------------------------------------------
__global__ __launch_bounds__(512, 2) void scores_kernel(
    const half_t* q16, const half_t* encsw, half_t* p16) {
    __shared__ float red[512];
    __shared__ float redg[64];

    const int l = blockIdx.x;
    const int xcd = l & 7, idx = l >> 3;
    const int b = xcd + ((idx >> 4) << 3);   // 2 batches per XCD: encsw L2-resident
    const int qbase = (idx & 15) * 64;

    const int tid = threadIdx.x;
    const int w = tid >> 6, lane = tid & 63, quad = lane >> 4, n16 = lane & 15;
    const int laneoff = n16 * 32 + quad * 8;   // frag lane offset within 1KB chunk
    const size_t bofs = (size_t)b << 20;

    f32x4 acc[4][8];
#pragma unroll
    for (int rb = 0; rb < 4; ++rb)
#pragma unroll
        for (int cf = 0; cf < 8; ++cf) acc[rb][cf] = (f32x4){0.f, 0.f, 0.f, 0.f};

    for (int dc = 0; dc < 32; ++dc) {
        const half_t* qc = q16 + bofs + (size_t)dc * 32768;
        const half_t* ec = encsw + bofs + (size_t)dc * 32768;
        f16x8 af[4], bf[8];
#pragma unroll
        for (int rb = 0; rb < 4; ++rb)
            af[rb] = *(const f16x8*)(qc + (qbase + rb * 16) * 32 + laneoff);
#pragma unroll
        for (int h = 0; h < 2; ++h)
#pragma unroll
            for (int cb = 0; cb < 4; ++cb)
                bf[h * 4 + cb] = *(const f16x8*)(
                    ec + (h * 512 + w * 64 + cb * 16) * 32 + laneoff);
#pragma unroll
        for (int rb = 0; rb < 4; ++rb)
#pragma unroll
            for (int cf = 0; cf < 8; ++cf)
                acc[rb][cf] = __builtin_amdgcn_mfma_f32_16x16x32_f16(
                    af[rb], bf[cf], acc[rb][cf], 0, 0, 0);
    }

    // ---- softmax over the 1024 cols held across the 8 waves ----
    float mrow[4][4], srow[4][4];
#pragma unroll
    for (int rb = 0; rb < 4; ++rb)
#pragma unroll
        for (int r = 0; r < 4; ++r) {
            float m = -1e30f;
#pragma unroll
            for (int cf = 0; cf < 8; ++cf) m = fmaxf(m, acc[rb][cf][r]);
#pragma unroll
            for (int off = 1; off < 16; off <<= 1)
                m = fmaxf(m, __shfl_xor(m, off, 64));
            mrow[rb][r] = m;
        }
    if (n16 == 0) {
#pragma unroll
        for (int rb = 0; rb < 4; ++rb)
#pragma unroll
            for (int r = 0; r < 4; ++r)
                red[w * 64 + rb * 16 + quad * 4 + r] = mrow[rb][r];
    }
    __syncthreads();
    if (tid < 64) {
        float g = red[tid];
#pragma unroll
        for (int ww = 1; ww < 8; ++ww) g = fmaxf(g, red[ww * 64 + tid]);
        redg[tid] = g;
    }
    __syncthreads();
#pragma unroll
    for (int rb = 0; rb < 4; ++rb)
#pragma unroll
        for (int r = 0; r < 4; ++r) mrow[rb][r] = redg[rb * 16 + quad * 4 + r];
    __syncthreads();  // maxes consumed; red reused for sums

#pragma unroll
    for (int rb = 0; rb < 4; ++rb)
#pragma unroll
        for (int r = 0; r < 4; ++r) {
            float s = 0.f;
#pragma unroll
            for (int cf = 0; cf < 8; ++cf) {
                float p = __expf(acc[rb][cf][r] - mrow[rb][r]);
                acc[rb][cf][r] = p;
                s += p;
            }
#pragma unroll
            for (int off = 1; off < 16; off <<= 1) s += __shfl_xor(s, off, 64);
            srow[rb][r] = s;
        }
    if (n16 == 0) {
#pragma unroll
        for (int rb = 0; rb < 4; ++rb)
#pragma unroll
            for (int r = 0; r < 4; ++r)
                red[w * 64 + rb * 16 + quad * 4 + r] = srow[rb][r];
    }
    __syncthreads();
    if (tid < 64) {
        float g = 0.f;
#pragma unroll
        for (int ww = 0; ww < 8; ++ww) g += red[ww * 64 + tid];
        redg[tid] = g;
    }
    __syncthreads();
#pragma unroll
    for (int rb = 0; rb < 4; ++rb)
#pragma unroll
        for (int r = 0; r < 4; ++r)
            srow[rb][r] = 1.0f / redg[rb * 16 + quad * 4 + r];

    // ---- store normalized P as fp16 in swizzled layout (ctx A-operand) ----
#pragma unroll
    for (int rb = 0; rb < 4; ++rb)
#pragma unroll
        for (int cf = 0; cf < 8; ++cf) {
            const int colbase = ((cf >> 2) << 9) + w * 64 + ((cf & 3) << 4);
            half_t* pp = p16 + bofs + (size_t)(colbase >> 5) * 32768
                         + (colbase & 31) + n16;
#pragma unroll
            for (int r = 0; r < 4; ++r) {
                const int row = qbase + rb * 16 + quad * 4 + r;
                pp[row * 32] = (half_t)(acc[rb][cf][r] * srow[rb][r]);
            }
        }
}

// ---------------------------------------------------------------------------
// Kernel 3: out = P16 @ enc (NT via encTsw). grid 512 x 256 thr (4 waves).
// Block tile 128q x 256d; wave (wr,wc) does 64q x 128d: acc[4][8] = 128 VGPR.
// K-loop: 12 coalesced frag loads + 32 MFMA per kc, no LDS, no barriers.
// ---------------------------------------------------------------------------
__global__ __launch_bounds__(256, 2) void ctx_kernel(
    const half_t* __restrict__ p16, const half_t* __restrict__ encTsw,
    float* __restrict__ out) {
    const int l = blockIdx.x;
    const int xcd = l & 7, idx = l >> 3;        // idx 0..63
    const int b = xcd + ((idx >> 5) << 3);
    const int rem = idx & 31;
    const int qt = rem >> 2, dt = rem & 3;
    const int tid = threadIdx.x;
    const int w = tid >> 6, lane = tid & 63, quad = lane >> 4, n16 = lane & 15;
    const int wr = w >> 1, wc = w & 1;
    const int laneoff = n16 * 32 + quad * 8;
    const size_t bofs = (size_t)b << 20;

    const int arow0 = qt * 128 + wr * 64;    // + rb*16
    const int brow0 = dt * 256 + wc * 128;   // + cb*16

    f32x4 acc[4][8];
#pragma unroll
    for (int i = 0; i < 4; ++i)
#pragma unroll
        for (int j = 0; j < 8; ++j) acc[i][j] = (f32x4){0.f, 0.f, 0.f, 0.f};

    for (int kc = 0; kc < 32; ++kc) {
        const half_t* ac = p16 + bofs + (size_t)kc * 32768;
        const half_t* bc = encTsw + bofs + (size_t)kc * 32768;
        f16x8 af[4], bf[8];
#pragma unroll
        for (int rb = 0; rb < 4; ++rb)
            af[rb] = *(const f16x8*)(ac + (arow0 + rb * 16) * 32 + laneoff);
#pragma unroll
        for (int cb = 0; cb < 8; ++cb)
            bf[cb] = *(const f16x8*)(bc + (brow0 + cb * 16) * 32 + laneoff);
#pragma unroll
        for (int rb = 0; rb < 4; ++rb)
#pragma unroll
            for (int cb = 0; cb < 8; ++cb)
                acc[rb][cb] = __builtin_amdgcn_mfma_f32_16x16x32_f16(
                    af[rb], bf[cb], acc[rb][cb], 0, 0, 0);
    }

#pragma unroll
    for (int rb = 0; rb < 4; ++rb)
#pragma unroll
        for (int cb = 0; cb < 8; ++cb)
#pragma unroll
            for (int r = 0; r < 4; ++r) {
                const int row = arow0 + rb * 16 + quad * 4 + r;
                const int col = brow0 + cb * 16 + n16;
                out[bofs + (size_t)row * 1024 + col] = acc[rb][cb][r];
            }
}

extern "C" void kernel_launch(void* const* d_in, const int* in_sizes, int n_in,
                              void* d_out, int out_size, void* d_ws, size_t ws_size,
                              hipStream_t stream) {
    (void)in_sizes; (void)n_in; (void)out_size; (void)ws_size;
    const float* dec = (const float*)d_in[0];   // decoder_hidden  [16,1024,1024] f32
    const float* enc = (const float*)d_in[1];   // encoder_outputs [16,1024,1024] f32
    float* out = (float*)d_out;

    // workspace: q16/p16 (aliased) | encsw | encTsw, 32MiB each (96MiB total)
    half_t* q16    = (half_t*)d_ws;
    half_t* p16    = q16;                        // alias: see header comment
    half_t* encsw  = q16 + ((size_t)16 << 20);
    half_t* encTsw = encsw + ((size_t)16 << 20);

    cvt_kernel<<<dim3(16, 16, 32), 256, 0, stream>>>(dec, enc, q16, encsw, encTsw);
    scores_kernel<<<dim3(256), 512, 0, stream>>>(q16, encsw, p16);
    ctx_kernel<<<dim3(512), 256, 0, stream>>>(p16, encTsw, out);
}